// Round 2
// baseline (653.012 us; speedup 1.0000x reference)
//
#include <hip/hip_runtime.h>
#include <math.h>

#define NPTS 400000
#define K27  27
#define NBLK 1568          // 8 XCD chunks x 196; 1568*256 = 401408 >= NPTS

typedef unsigned short u16;
typedef __bf16 bf16x8 __attribute__((ext_vector_type(8)));
typedef float  f32x4  __attribute__((ext_vector_type(4)));

__device__ __forceinline__ u16 f2bf(float f) {
    unsigned u = __float_as_uint(f);
    u += 0x7FFFu + ((u >> 16) & 1u);   // RNE round to bf16
    return (u16)(u >> 16);
}
__device__ __forceinline__ unsigned pack2(float lo, float hi) {
    return (unsigned)f2bf(lo) | ((unsigned)f2bf(hi) << 16);
}

// ---------------------------------------------------------------------------
// prep: transpose+pad W1 [27][64][38] -> W1t [27][48][64] bf16 (n-major, k-contig)
//       and W2 [27][38][38] -> W2t [27][48][64] bf16; also zero h row N.
// ---------------------------------------------------------------------------
__global__ void prep_w(const float* __restrict__ W1, const float* __restrict__ W2,
                       u16* __restrict__ W1t, u16* __restrict__ W2t,
                       u16* __restrict__ h)
{
    int i = blockIdx.x * 256 + threadIdx.x;
    if (blockIdx.x == 0 && threadIdx.x < 64)
        h[(size_t)NPTS * 64 + threadIdx.x] = 0;   // zero pad-row of h
    const int TOT = K27 * 48 * 64;
    if (i >= TOT) return;
    int k  = i / (48 * 64);
    int r  = i % (48 * 64);
    int n  = r >> 6;    // 0..47 (out channel)
    int kc = r & 63;    // 0..63 (in channel)
    u16 w1 = 0, w2 = 0;
    if (n < 38) {
        w1 = f2bf(W1[(k * 64 + kc) * 38 + n]);
        if (kc < 38) w2 = f2bf(W2[(k * 38 + kc) * 38 + n]);
    }
    W1t[i] = w1;
    W2t[i] = w2;
}

// ---------------------------------------------------------------------------
// prep: features fp32 [N][64] -> bf16 [N+1][64] (row N zeroed), 8 elems/thread
// ---------------------------------------------------------------------------
__global__ void prep_feat(const float* __restrict__ F, u16* __restrict__ Fb)
{
    size_t i = (size_t)blockIdx.x * 256 + threadIdx.x;     // chunk of 8 elems
    const size_t TOTV = (size_t)NPTS * 8;                  // valid chunks
    const size_t TOT  = (size_t)(NPTS + 1) * 8;
    if (i >= TOT) return;
    uint4 v = {0, 0, 0, 0};
    if (i < TOTV) {
        const float4* fp = (const float4*)(F + i * 8);
        float4 a = fp[0], b = fp[1];
        v.x = pack2(a.x, a.y); v.y = pack2(a.z, a.w);
        v.z = pack2(b.x, b.y); v.w = pack2(b.z, b.w);
    }
    *(uint4*)(Fb + i * 8) = v;
}

// ---------------------------------------------------------------------------
// Barrier-free register-direct gather-GEMM layer.
// 1 wave = 64 points x 48 (padded) out channels; block = 4 waves = 256 points.
// A fragment (16B) gathered straight from the feature row; B (16B) straight
// from Wt (L2-resident). No LDS, no __syncthreads.
// LAYER==1: GELU -> h bf16 [N+1][64] (cols>=38 zero)
// LAYER==2: fp32 out [N][38]
// ---------------------------------------------------------------------------
template<int LAYER, bool BF16IN>
__global__ __launch_bounds__(256)
void spconv(const void* __restrict__ in_, const int* __restrict__ nbr,
            const u16* __restrict__ Wt, void* __restrict__ out_)
{
    const int t    = threadIdx.x;
    const int wave = t >> 6;
    const int lane = t & 63;
    const int quad = lane >> 4;
    const int l16  = lane & 15;

    // XCD-chunk swizzle: physical b%8 -> XCD id (round-robin heuristic);
    // give each XCD a contiguous range of points for L2 locality.
    const int b       = blockIdx.x;
    const int logical = (b & 7) * (NBLK / 8) + (b >> 3);
    const int wbase   = logical * 256 + wave * 64;   // this wave's first point

    f32x4 acc[4][3] = {};   // [m-tile][n-tile]

    int nrow[4];
    #pragma unroll
    for (int mt = 0; mt < 4; ++mt) {
        int r = wbase + mt * 16 + l16;
        nrow[mt] = (r < NPTS) ? r : (NPTS - 1);      // clamp; result discarded
    }

    int idx[4];
    #pragma unroll
    for (int mt = 0; mt < 4; ++mt) idx[mt] = nbr[nrow[mt]];

    for (int k = 0; k < K27; ++k) {
        // prefetch next offset's indices (independent of this iteration)
        int idxn[4] = {0, 0, 0, 0};
        if (k + 1 < K27) {
            #pragma unroll
            for (int mt = 0; mt < 4; ++mt)
                idxn[mt] = nbr[(size_t)(k + 1) * NPTS + nrow[mt]];
        }

        // ---- A fragments: direct global gather, 2 x 16B per m-tile ----
        bf16x8 A[4][2];
        #pragma unroll
        for (int mt = 0; mt < 4; ++mt) {
            if (BF16IN) {
                const u16* rowp = (const u16*)in_ + (size_t)idx[mt] * 64 + quad * 8;
                A[mt][0] = *(const bf16x8*)(rowp);
                A[mt][1] = *(const bf16x8*)(rowp + 32);
            } else {
                int ic = idx[mt] < NPTS ? idx[mt] : NPTS - 1;
                const float* rowp = (const float*)in_ + (size_t)ic * 64 + quad * 8;
                float4 f0 = *(const float4*)(rowp);
                float4 f1 = *(const float4*)(rowp + 4);
                float4 f2 = *(const float4*)(rowp + 32);
                float4 f3 = *(const float4*)(rowp + 36);
                uint4 v0, v1;
                v0.x = pack2(f0.x, f0.y); v0.y = pack2(f0.z, f0.w);
                v0.z = pack2(f1.x, f1.y); v0.w = pack2(f1.z, f1.w);
                v1.x = pack2(f2.x, f2.y); v1.y = pack2(f2.z, f2.w);
                v1.z = pack2(f3.x, f3.y); v1.w = pack2(f3.z, f3.w);
                if (idx[mt] >= NPTS) { v0 = uint4{0,0,0,0}; v1 = uint4{0,0,0,0}; }
                A[mt][0] = *(const bf16x8*)&v0;
                A[mt][1] = *(const bf16x8*)&v1;
            }
        }

        // ---- B fragments: direct from Wt (L2-hot), 2 x 16B per n-tile ----
        const u16* wk = Wt + (size_t)k * 48 * 64;
        bf16x8 B[3][2];
        #pragma unroll
        for (int nt = 0; nt < 3; ++nt) {
            const u16* brow = wk + (nt * 16 + l16) * 64 + quad * 8;
            B[nt][0] = *(const bf16x8*)(brow);
            B[nt][1] = *(const bf16x8*)(brow + 32);
        }

        // ---- MFMA ----
        #pragma unroll
        for (int mt = 0; mt < 4; ++mt)
            #pragma unroll
            for (int nt = 0; nt < 3; ++nt) {
                acc[mt][nt] = __builtin_amdgcn_mfma_f32_16x16x32_bf16(A[mt][0], B[nt][0], acc[mt][nt], 0, 0, 0);
                acc[mt][nt] = __builtin_amdgcn_mfma_f32_16x16x32_bf16(A[mt][1], B[nt][1], acc[mt][nt], 0, 0, 0);
            }

        #pragma unroll
        for (int mt = 0; mt < 4; ++mt) idx[mt] = idxn[mt];
    }

    // ---- epilogue ----
    if (LAYER == 1) {
        u16* h = (u16*)out_;
        #pragma unroll
        for (int mt = 0; mt < 4; ++mt) {
            int row0 = wbase + mt * 16 + quad * 4;
            #pragma unroll
            for (int r = 0; r < 4; ++r) {
                int row = row0 + r;
                if (row < NPTS) {
                    #pragma unroll
                    for (int nt = 0; nt < 3; ++nt) {
                        float x = acc[mt][nt][r];
                        float g = 0.5f * x * (1.0f + erff(x * 0.70710678118654752f));
                        h[(size_t)row * 64 + nt * 16 + l16] = f2bf(g);
                    }
                    h[(size_t)row * 64 + 48 + l16] = 0;   // zero pad cols 48..63
                }
            }
        }
    } else {
        float* out = (float*)out_;
        #pragma unroll
        for (int mt = 0; mt < 4; ++mt) {
            int row0 = wbase + mt * 16 + quad * 4;
            #pragma unroll
            for (int nt = 0; nt < 3; ++nt) {
                int col = nt * 16 + l16;
                if (col < 38) {
                    #pragma unroll
                    for (int r = 0; r < 4; ++r) {
                        int row = row0 + r;
                        if (row < NPTS)
                            out[(size_t)row * 38 + col] = acc[mt][nt][r];
                    }
                }
            }
        }
    }
}

// ---------------------------------------------------------------------------
extern "C" void kernel_launch(void* const* d_in, const int* in_sizes, int n_in,
                              void* d_out, int out_size, void* d_ws, size_t ws_size,
                              hipStream_t stream)
{
    const float* feat = (const float*)d_in[0];   // [N][64] fp32
    const int*   nbr  = (const int*)  d_in[1];   // [27][N] int32, N == pad idx
    const float* W1   = (const float*)d_in[2];   // [27][64][38]
    const float* W2   = (const float*)d_in[3];   // [27][38][38]

    const size_t hbytes = (size_t)(NPTS + 1) * 64 * 2;   // h: N+1 rows bf16
    const size_t wbytes = (size_t)K27 * 48 * 64 * 2;     // 165,888

    char* ws = (char*)d_ws;
    u16* h   = (u16*)ws;
    u16* W1t = (u16*)(ws + hbytes);
    u16* W2t = (u16*)(ws + hbytes + wbytes);
    u16* Fb  = (u16*)(ws + hbytes + 2 * wbytes);
    const bool full = ws_size >= 2 * hbytes + 2 * wbytes;  // bf16 feature copy fits?

    prep_w<<<(K27 * 48 * 64 + 255) / 256, 256, 0, stream>>>(W1, W2, W1t, W2t, h);

    if (full) {
        prep_feat<<<(int)(((size_t)(NPTS + 1) * 8 + 255) / 256), 256, 0, stream>>>(feat, Fb);
        spconv<1, true ><<<NBLK, 256, 0, stream>>>(Fb,   nbr, W1t, h);
    } else {
        spconv<1, false><<<NBLK, 256, 0, stream>>>(feat, nbr, W1t, h);
    }
    spconv<2, true ><<<NBLK, 256, 0, stream>>>(h, nbr, W2t, d_out);
}